// Round 1
// baseline (271.714 us; speedup 1.0000x reference)
//
#include <hip/hip_runtime.h>
#include <stdint.h>

// ---------- types ----------
typedef __bf16 bf16x8 __attribute__((ext_vector_type(8)));
typedef float f32x4 __attribute__((ext_vector_type(4)));
typedef unsigned short u16x8 __attribute__((ext_vector_type(8)));
typedef unsigned int as1_uint __attribute__((address_space(1)));
typedef unsigned int as3_uint __attribute__((address_space(3)));

#define N_B 32768
#define S_IN 256
#define H_DIM 512
#define A_DIM 64
#define K1_DIM 2304   // 9 * 256
#define K2_DIM 4608   // 9 * 512

static __device__ __forceinline__ unsigned short f2bf(float f) {
  union { float f; unsigned u; } v; v.f = f;
  unsigned r = v.u + 0x7fffu + ((v.u >> 16) & 1u);
  return (unsigned short)(r >> 16);
}

static __device__ __forceinline__ void gload_lds16(const void* g, void* l) {
  __builtin_amdgcn_global_load_lds((const as1_uint*)g, (as3_uint*)l, 16, 0, 0);
}

// Uniform-knot cardinal cubic B-spline: u = 2.5x + 5.5, c = floor(u), f = u-c.
// Nonzero bases g = c-3..c ; weight for g=c is w3 (f^3/6), g=c-1 -> w2, g=c-2 -> w1,
// g=c-3 -> w0 ((1-f)^3/6). Exactly equals the reference Cox-de Boor recursion
// (half-open degree-0 intervals make the support truncation automatic).
static __device__ __forceinline__ void bspline_w(float x, float& c,
    float& w0, float& w1, float& w2, float& w3) {
  float u = fmaf(2.5f, x, 5.5f);
  c = floorf(u);
  float f = u - c;
  float f2 = f * f;
  float f3 = f2 * f;
  const float k6 = 1.f / 6.f;
  w3 = f3 * k6;
  w2 = (3.f * (f + f2 - f3) + 1.f) * k6;   // (-3f^3+3f^2+3f+1)/6
  w1 = (3.f * f3 - 6.f * f2 + 4.f) * k6;   // (3f^3-6f^2+4)/6
  float omf = 1.f - f;
  w0 = omf * omf * omf * k6;
}

static __device__ __forceinline__ float silu_f(float x) {
  return x / (1.f + __expf(-x));
}

// ---------- sentinel (workspace too small diagnostic) ----------
__global__ void k_sentinel(float* out, int n) {
  int i = blockIdx.x * blockDim.x + threadIdx.x;
  for (; i < n; i += gridDim.x * blockDim.x) out[i] = 12345.f;
}

// ---------- weight prep: f32 -> bf16, feature-plane-major K layout ----------
// W1[n][k], n in [0,512), k = j*256 + i ; j=0: base_w, j>=1: spline_w[:, :, j-1]
__global__ void k_prep_w1(const float* __restrict__ base_w,
                          const float* __restrict__ spline_w,
                          unsigned short* __restrict__ W1) {
  int idx = blockIdx.x * blockDim.x + threadIdx.x;   // 512*2304 = 1179648
  int n = idx / K1_DIM;
  int k = idx - n * K1_DIM;
  int j = k >> 8;
  int i = k & 255;
  float v = (j == 0) ? base_w[n * S_IN + i]
                     : spline_w[(size_t)(n * S_IN + i) * 8 + (j - 1)];
  W1[idx] = f2bf(v);
}

// W2[n][k], n in [0,128) (0..63 mean, 64..127 lstd), k = j*512 + h
__global__ void k_prep_w2(const float* __restrict__ mean_base,
                          const float* __restrict__ mean_spl,
                          const float* __restrict__ lstd_base,
                          const float* __restrict__ lstd_spl,
                          unsigned short* __restrict__ W2) {
  int idx = blockIdx.x * blockDim.x + threadIdx.x;   // 128*4608 = 589824
  int n = idx / K2_DIM;
  int k = idx - n * K2_DIM;
  int j = k >> 9;
  int h = k & 511;
  const float* bw = (n < 64) ? mean_base : lstd_base;
  const float* sw = (n < 64) ? mean_spl : lstd_spl;
  int nn = n & 63;
  float v = (j == 0) ? bw[nn * H_DIM + h]
                     : sw[(size_t)(nn * H_DIM + h) * 8 + (j - 1)];
  W2[idx] = f2bf(v);
}

// ---------- layer-1 feature expansion: state[B][256] -> F1[B][9*256] bf16 ----------
__global__ void k_features1(const float* __restrict__ state,
                            unsigned short* __restrict__ F1) {
  int tid = blockIdx.x * blockDim.x + threadIdx.x;   // < 2097152
  int base = tid * 4;
  int b = base >> 8;
  int i = base & 255;
  const float4 xv = *(const float4*)(state + base);
  float xs[4] = {xv.x, xv.y, xv.z, xv.w};
  unsigned short outj[9][4];
  #pragma unroll
  for (int e = 0; e < 4; ++e) {
    float x = xs[e];
    float c, w0, w1, w2, w3;
    bspline_w(x, c, w0, w1, w2, w3);
    outj[0][e] = f2bf(silu_f(x));
    #pragma unroll
    for (int g = 0; g < 8; ++g) {
      float d = c - (float)g;
      float v = 0.f;
      v = (d == 0.f) ? w3 : v;
      v = (d == 1.f) ? w2 : v;
      v = (d == 2.f) ? w1 : v;
      v = (d == 3.f) ? w0 : v;
      outj[g + 1][e] = f2bf(v);
    }
  }
  size_t rowbase = (size_t)b * K1_DIM + i;
  #pragma unroll
  for (int j = 0; j < 9; ++j) {
    *(ushort4*)(F1 + rowbase + j * S_IN) =
        make_ushort4(outj[j][0], outj[j][1], outj[j][2], outj[j][3]);
  }
}

// ---------- GEMM1: X[32768][512] = F1[32768][2304] @ W1[512][2304]^T ----------
// m97-style: 128x128 tile, BK=64, double-buffered global_load_lds(16B), 4 waves.
__global__ __launch_bounds__(256, 2) void k_gemm1(
    const unsigned short* __restrict__ F1,
    const unsigned short* __restrict__ W1,
    float* __restrict__ X) {
  extern __shared__ unsigned short smem[];
  unsigned short* As0 = smem;            // [128][64]
  unsigned short* As1 = smem + 8192;
  unsigned short* Bs0 = smem + 16384;    // [128][64]
  unsigned short* Bs1 = smem + 24576;

  const int t = threadIdx.x;
  const int bm = blockIdx.x >> 2;        // 0..255
  const int bn = blockIdx.x & 3;         // 0..3

  const unsigned short* Ab = F1 + (size_t)bm * 128 * K1_DIM;
  const unsigned short* Bb = W1 + (size_t)bn * 128 * K1_DIM;

  const int srow = t >> 3;               // 0..31
  const int scol = (t & 7) * 8;          // element offset (16B chunks)

  auto stage = [&](int buf, int kt) {
    unsigned short* Ad = buf ? As1 : As0;
    unsigned short* Bd = buf ? Bs1 : Bs0;
    const size_t k0 = (size_t)kt * 64;
    #pragma unroll
    for (int q = 0; q < 4; ++q) {
      const int r = q * 32 + srow;
      gload_lds16(Ab + (size_t)r * K1_DIM + k0 + scol, Ad + r * 64 + scol);
      gload_lds16(Bb + (size_t)r * K1_DIM + k0 + scol, Bd + r * 64 + scol);
    }
  };

  const int wave = t >> 6;
  const int lane = t & 63;
  const int wm = (wave >> 1) * 64;
  const int wn = (wave & 1) * 64;
  const int lr = lane & 15;
  const int lk = (lane >> 4) * 8;

  f32x4 acc[4][4];
  #pragma unroll
  for (int i = 0; i < 4; ++i)
    #pragma unroll
    for (int jj = 0; jj < 4; ++jj)
      acc[i][jj] = (f32x4){0.f, 0.f, 0.f, 0.f};

  stage(0, 0);
  __syncthreads();
  int cur = 0;
  const int NT = K1_DIM / 64;            // 36
  for (int kt = 0; kt < NT; ++kt) {
    if (kt + 1 < NT) stage(cur ^ 1, kt + 1);
    const unsigned short* A0 = cur ? As1 : As0;
    const unsigned short* B0 = cur ? Bs1 : Bs0;
    #pragma unroll
    for (int ks = 0; ks < 2; ++ks) {
      bf16x8 af[4], bfv[4];
      #pragma unroll
      for (int fm = 0; fm < 4; ++fm)
        af[fm] = *(const bf16x8*)(A0 + (wm + fm * 16 + lr) * 64 + ks * 32 + lk);
      #pragma unroll
      for (int fn = 0; fn < 4; ++fn)
        bfv[fn] = *(const bf16x8*)(B0 + (wn + fn * 16 + lr) * 64 + ks * 32 + lk);
      #pragma unroll
      for (int fm = 0; fm < 4; ++fm)
        #pragma unroll
        for (int fn = 0; fn < 4; ++fn)
          acc[fm][fn] = __builtin_amdgcn_mfma_f32_16x16x32_bf16(
              af[fm], bfv[fn], acc[fm][fn], 0, 0, 0);
    }
    __syncthreads();
    cur ^= 1;
  }

  // C/D layout: col = lane&15, row = (lane>>4)*4 + reg   [m89-verified]
  float* Xb = X + (size_t)bm * 128 * H_DIM + bn * 128;
  #pragma unroll
  for (int fm = 0; fm < 4; ++fm) {
    const int row0 = wm + fm * 16 + (lane >> 4) * 4;
    #pragma unroll
    for (int fn = 0; fn < 4; ++fn) {
      const int col = wn + fn * 16 + lr;
      #pragma unroll
      for (int r = 0; r < 4; ++r)
        Xb[(size_t)(row0 + r) * H_DIM + col] = acc[fm][fn][r];
    }
  }
}

// ---------- GEMM2 (fused LN+relu+feature-expansion): out = heads(F2(X)) ----------
// Block: 64 rows x 128 out-cols, K = 4608 (j-major). Per-thread spline-weight stash
// computed once per h-block (j==0), cheap select for j=1..8.
__global__ __launch_bounds__(256, 2) void k_gemm2(
    const float* __restrict__ X, const unsigned short* __restrict__ W2,
    const float* __restrict__ gamma, const float* __restrict__ beta,
    float* __restrict__ out) {
  extern __shared__ unsigned short smem2[];
  unsigned short* At = smem2;            // [64][64]
  unsigned short* Bt = smem2 + 64 * 64;  // [128][64]

  const int t = threadIdx.x;
  const int bm = blockIdx.x;             // 0..511
  const int row = t >> 2;                // local row 0..63
  const int quart = t & 3;
  const int wave = t >> 6;
  const int lane = t & 63;
  const int wn = wave * 32;
  const int lr = lane & 15;
  const int lk = (lane >> 4) * 8;

  const float* Xrow = X + (size_t)(bm * 64 + row) * H_DIM;

  // phase 0: row stats (mean/var over 512), 4 threads per row
  float s = 0.f, ss = 0.f;
  #pragma unroll 4
  for (int q = 0; q < 32; ++q) {
    float4 v = *(const float4*)(Xrow + quart * 128 + q * 4);
    s += v.x + v.y + v.z + v.w;
    ss += v.x * v.x + v.y * v.y + v.z * v.z + v.w * v.w;
  }
  s += __shfl_xor(s, 1); ss += __shfl_xor(ss, 1);
  s += __shfl_xor(s, 2); ss += __shfl_xor(ss, 2);
  const float mu = s * (1.f / 512.f);
  const float var = ss * (1.f / 512.f) - mu * mu;
  const float rstd = rsqrtf(var + 1e-5f);

  f32x4 acc[4][2];
  #pragma unroll
  for (int i = 0; i < 4; ++i)
    #pragma unroll
    for (int jj = 0; jj < 2; ++jj)
      acc[i][jj] = (f32x4){0.f, 0.f, 0.f, 0.f};

  float cw[16], w0[16], w1[16], w2[16], w3[16];

  const int sbrow = t >> 3;
  const int sbcol = (t & 7) * 8;

  for (int hb = 0; hb < 8; ++hb) {
    for (int j = 0; j < 9; ++j) {
      __syncthreads();   // prior MFMA reads drained before overwrite
      // stage B tile: W2 rows 0..127, k = j*512 + hb*64 + [0,64)
      {
        const size_t k0 = (size_t)j * 512 + hb * 64;
        #pragma unroll
        for (int q = 0; q < 4; ++q) {
          const int r = q * 32 + sbrow;
          gload_lds16(W2 + (size_t)r * K2_DIM + k0 + sbcol, Bt + r * 64 + sbcol);
        }
      }
      // stage A tile: features of normalized x (thread owns row, 16 h's)
      unsigned short av[16];
      if (j == 0) {
        #pragma unroll
        for (int c4 = 0; c4 < 4; ++c4) {
          const int h = hb * 64 + quart * 16 + c4 * 4;
          const float4 xv = *(const float4*)(Xrow + h);
          const float4 gv = *(const float4*)(gamma + h);
          const float4 bv = *(const float4*)(beta + h);
          float xa[4] = {xv.x, xv.y, xv.z, xv.w};
          float ga[4] = {gv.x, gv.y, gv.z, gv.w};
          float ba[4] = {bv.x, bv.y, bv.z, bv.w};
          #pragma unroll
          for (int e2 = 0; e2 < 4; ++e2) {
            const int e = c4 * 4 + e2;
            float xn = fmaf((xa[e2] - mu) * rstd, ga[e2], ba[e2]);
            xn = fmaxf(xn, 0.f);                 // relu
            bspline_w(xn, cw[e], w0[e], w1[e], w2[e], w3[e]);
            av[e] = f2bf(silu_f(xn));
          }
        }
      } else {
        const float g = (float)(j - 1);
        #pragma unroll
        for (int e = 0; e < 16; ++e) {
          const float d = cw[e] - g;
          float v = 0.f;
          v = (d == 0.f) ? w3[e] : v;
          v = (d == 1.f) ? w2[e] : v;
          v = (d == 2.f) ? w1[e] : v;
          v = (d == 3.f) ? w0[e] : v;
          av[e] = f2bf(v);
        }
      }
      u16x8 p0, p1;
      #pragma unroll
      for (int e = 0; e < 8; ++e) { p0[e] = av[e]; p1[e] = av[e + 8]; }
      *(u16x8*)(At + row * 64 + quart * 16) = p0;
      *(u16x8*)(At + row * 64 + quart * 16 + 8) = p1;

      __syncthreads();   // drains gload_lds (vmcnt) + ds_writes (lgkm)

      #pragma unroll
      for (int ks = 0; ks < 2; ++ks) {
        bf16x8 af[4], bfv[2];
        #pragma unroll
        for (int fm = 0; fm < 4; ++fm)
          af[fm] = *(const bf16x8*)(At + (fm * 16 + lr) * 64 + ks * 32 + lk);
        #pragma unroll
        for (int fn = 0; fn < 2; ++fn)
          bfv[fn] = *(const bf16x8*)(Bt + (wn + fn * 16 + lr) * 64 + ks * 32 + lk);
        #pragma unroll
        for (int fm = 0; fm < 4; ++fm)
          #pragma unroll
          for (int fn = 0; fn < 2; ++fn)
            acc[fm][fn] = __builtin_amdgcn_mfma_f32_16x16x32_bf16(
                af[fm], bfv[fn], acc[fm][fn], 0, 0, 0);
      }
    }
  }

  // epilogue: cols 0..63 -> tanh -> mean ; 64..127 -> clip -> log_std
  float* mean_out = out;
  float* lstd_out = out + (size_t)N_B * A_DIM;
  #pragma unroll
  for (int fm = 0; fm < 4; ++fm) {
    const int r0 = bm * 64 + fm * 16 + (lane >> 4) * 4;
    #pragma unroll
    for (int fn = 0; fn < 2; ++fn) {
      const int n = wn + fn * 16 + lr;
      #pragma unroll
      for (int r = 0; r < 4; ++r) {
        const float v = acc[fm][fn][r];
        if (n < 64) mean_out[(size_t)(r0 + r) * 64 + n] = tanhf(v);
        else lstd_out[(size_t)(r0 + r) * 64 + (n - 64)] = fminf(fmaxf(v, -20.f), 2.f);
      }
    }
  }
}

// ---------- launch ----------
extern "C" void kernel_launch(void* const* d_in, const int* in_sizes, int n_in,
                              void* d_out, int out_size, void* d_ws, size_t ws_size,
                              hipStream_t stream) {
  const float* state         = (const float*)d_in[0];
  const float* feat_base_w   = (const float*)d_in[1];
  const float* feat_spline_w = (const float*)d_in[2];
  const float* ln_gamma      = (const float*)d_in[3];
  const float* ln_beta       = (const float*)d_in[4];
  const float* mean_base_w   = (const float*)d_in[5];
  const float* mean_spline_w = (const float*)d_in[6];
  const float* lstd_base_w   = (const float*)d_in[7];
  const float* lstd_spline_w = (const float*)d_in[8];
  // d_in[9] = grid_size (5), d_in[10] = spline_order (3): compile-time constants here.

  // workspace layout (bytes)
  const size_t W1_OFF = 0;               // 512*2304*2  = 2359296
  const size_t W2_OFF = 2359296;         // 128*4608*2  = 1179648
  const size_t F1_OFF = 3538944;         // 32768*2304*2 = 150994944
  const size_t X_OFF  = 154533888;       // 32768*512*4 = 67108864
  const size_t NEED   = 221642752;

  if (ws_size < NEED) {
    hipLaunchKernelGGL(k_sentinel, dim3(4096), dim3(256), 0, stream,
                       (float*)d_out, out_size);
    return;
  }

  char* ws = (char*)d_ws;
  unsigned short* W1 = (unsigned short*)(ws + W1_OFF);
  unsigned short* W2 = (unsigned short*)(ws + W2_OFF);
  unsigned short* F1 = (unsigned short*)(ws + F1_OFF);
  float* X = (float*)(ws + X_OFF);

  hipLaunchKernelGGL(k_prep_w1, dim3(4608), dim3(256), 0, stream,
                     feat_base_w, feat_spline_w, W1);
  hipLaunchKernelGGL(k_prep_w2, dim3(2304), dim3(256), 0, stream,
                     mean_base_w, mean_spline_w, lstd_base_w, lstd_spline_w, W2);
  hipLaunchKernelGGL(k_features1, dim3(8192), dim3(256), 0, stream, state, F1);
  hipLaunchKernelGGL(k_gemm1, dim3(1024), dim3(256), 65536, stream, F1, W1, X);
  hipLaunchKernelGGL(k_gemm2, dim3(512), dim3(256), 24576, stream,
                     X, W2, ln_gamma, ln_beta, (float*)d_out);
}